// Round 1
// baseline (99.105 us; speedup 1.0000x reference)
//
#include <hip/hip_runtime.h>
#include <stdint.h>

#define CI 256
#define CO 256
#define HW 4096          // 64*64 pixels per image
#define PT 64            // pixel tile per block
#define QPAD 72          // Qlds row stride in shorts: 144 B, 16B-aligned

typedef __attribute__((ext_vector_type(8))) short short8;   // 8 bf16 = 4 VGPRs
typedef __attribute__((ext_vector_type(4))) float float4v;  // MFMA C/D frag

// ---------- weight prep: fp32 -> bf16 (RNE) + per-row sums ----------
__global__ void prep_kernel(const float* __restrict__ w,
                            ushort* __restrict__ w16,
                            float* __restrict__ wsum) {
    const int o = blockIdx.x;        // one output row per 64-thread block
    const int lane = threadIdx.x;    // 0..63
    float4 v = ((const float4*)(w + o * CI))[lane];
    auto cvt = [](float f) -> ushort {
        uint32_t u = __float_as_uint(f);
        return (ushort)((u + 0x7FFFu + ((u >> 16) & 1u)) >> 16);   // RNE
    };
    ushort4 q;
    q.x = cvt(v.x); q.y = cvt(v.y); q.z = cvt(v.z); q.w = cvt(v.w);
    ((ushort4*)(w16 + o * CI))[lane] = q;
    float s = v.x + v.y + v.z + v.w;
    for (int off = 32; off >= 1; off >>= 1) s += __shfl_down(s, off);
    if (lane == 0) wsum[o] = s;
}

// ---------- fused quantize + 1x1-conv GEMM ----------
__global__ __launch_bounds__(256, 2)
void noise_conv_kernel(const float* __restrict__ x,
                       const ushort* __restrict__ w16,
                       const float* __restrict__ wsum,
                       const float* __restrict__ bias,
                       float* __restrict__ out) {
    __shared__ ushort Qlds[PT][QPAD];          // quantized bf16 tile [p][c]
    __shared__ float4 rmin4[16][16];           // [slice][pixel-group]
    __shared__ float4 rmax4[16][16];
    __shared__ float cmin_s[PT], s_s[PT], inv_s[PT];

    const int t = threadIdx.x;
    const int blk = blockIdx.x;                // 512 = 8 imgs * 64 tiles
    const int img = blk >> 6;
    const int p0 = (blk & 63) * PT;
    const float* xb = x + (size_t)img * CI * HW + p0;
    float* outb = out + (size_t)img * CO * HW + p0;

    // ---- phase 1: per-pixel min/max over 256 channels ----
    {
        const int pg = t & 15;        // 4-pixel group (float4)
        const int slice = t >> 4;     // 16 slices x 16 channels
        float4 vmin = make_float4(__builtin_inff(), __builtin_inff(),
                                  __builtin_inff(), __builtin_inff());
        float4 vmax = make_float4(-__builtin_inff(), -__builtin_inff(),
                                  -__builtin_inff(), -__builtin_inff());
        #pragma unroll
        for (int i = 0; i < 16; ++i) {
            const float4 v = ((const float4*)(xb + (size_t)(slice * 16 + i) * HW))[pg];
            vmin.x = fminf(vmin.x, v.x); vmax.x = fmaxf(vmax.x, v.x);
            vmin.y = fminf(vmin.y, v.y); vmax.y = fmaxf(vmax.y, v.y);
            vmin.z = fminf(vmin.z, v.z); vmax.z = fmaxf(vmax.z, v.z);
            vmin.w = fminf(vmin.w, v.w); vmax.w = fmaxf(vmax.w, v.w);
        }
        rmin4[slice][pg] = vmin;
        rmax4[slice][pg] = vmax;
    }
    __syncthreads();
    if (t < 16) {
        float4 mn = rmin4[0][t], mx = rmax4[0][t];
        for (int sl = 1; sl < 16; ++sl) {
            float4 a = rmin4[sl][t], b = rmax4[sl][t];
            mn.x = fminf(mn.x, a.x); mx.x = fmaxf(mx.x, b.x);
            mn.y = fminf(mn.y, a.y); mx.y = fmaxf(mx.y, b.y);
            mn.z = fminf(mn.z, a.z); mx.z = fmaxf(mx.z, b.z);
            mn.w = fminf(mn.w, a.w); mx.w = fmaxf(mx.w, b.w);
        }
        const float mnv[4] = {mn.x, mn.y, mn.z, mn.w};
        const float mxv[4] = {mx.x, mx.y, mx.z, mx.w};
        #pragma unroll
        for (int c = 0; c < 4; ++c) {
            const int p = t * 4 + c;
            const float cmin = mnv[c];
            const float sc = (mxv[c] - cmin) / 63.0f;   // match ref: /63
            cmin_s[p] = cmin;
            s_s[p] = sc;
            inv_s[p] = 1.0f / sc;
        }
    }
    __syncthreads();

    // ---- phase 2: K-chunked quantize -> LDS -> MFMA ----
    const int lane = t & 63;
    const int wv = t >> 6;           // wave 0..3 -> output rows [64w, 64w+64)
    const int row16 = lane & 15;
    const int quad = lane >> 4;

    float4v acc[4][4];
    #pragma unroll
    for (int m = 0; m < 4; ++m)
        #pragma unroll
        for (int n = 0; n < 4; ++n) {
            float4v z = {0.0f, 0.0f, 0.0f, 0.0f};
            acc[m][n] = z;
        }

    const int sp = t & 63;           // staging: this thread's pixel
    const int scb = (t >> 6) * 16;   // staging: c sub-range base in chunk
    const float cm = cmin_s[sp];
    const float iv = inv_s[sp];

    for (int c0 = 0; c0 < CI; c0 += 64) {
        // stage quantized bf16 tile Qlds[p][c] (64x64)
        #pragma unroll
        for (int jj = 0; jj < 2; ++jj) {
            uint32_t wds[4];
            #pragma unroll
            for (int j2 = 0; j2 < 4; ++j2) {
                const int c = c0 + scb + jj * 8 + j2 * 2;
                const float a0 = xb[(size_t)c * HW + sp];
                const float a1 = xb[(size_t)(c + 1) * HW + sp];
                const float q0 = rintf((a0 - cm) * iv);
                const float q1 = rintf((a1 - cm) * iv);
                const uint32_t b0 = __float_as_uint(q0) >> 16;   // exact bf16
                const uint32_t b1 = __float_as_uint(q1) >> 16;
                wds[j2] = b0 | (b1 << 16);
            }
            *((uint4*)&Qlds[sp][scb + jj * 8]) =
                make_uint4(wds[0], wds[1], wds[2], wds[3]);
        }
        __syncthreads();

        // compute: 2 k-steps of 32 within the 64-chunk
        #pragma unroll
        for (int ks = 0; ks < 2; ++ks) {
            const int kk = ks * 32 + quad * 8;
            short8 afr[4], bfr[4];
            #pragma unroll
            for (int m = 0; m < 4; ++m) {
                const int o = wv * 64 + m * 16 + row16;
                afr[m] = *((const short8*)(w16 + o * CI + c0 + kk));
            }
            #pragma unroll
            for (int n = 0; n < 4; ++n) {
                bfr[n] = *((const short8*)&Qlds[n * 16 + row16][kk]);
            }
            #pragma unroll
            for (int m = 0; m < 4; ++m)
                #pragma unroll
                for (int n = 0; n < 4; ++n)
                    acc[m][n] = __builtin_amdgcn_mfma_f32_16x16x32_bf16(
                        afr[m], bfr[n], acc[m][n], 0, 0, 0);
        }
        __syncthreads();
    }

    // ---- epilogue: rescale + cmin*wsum + bias, store ----
    #pragma unroll
    for (int m = 0; m < 4; ++m) {
        const int ob = wv * 64 + m * 16 + quad * 4;
        const float4 w4 = *((const float4*)(wsum + ob));
        const float4 b4 = *((const float4*)(bias + ob));
        const float wr[4] = {w4.x, w4.y, w4.z, w4.w};
        const float br[4] = {b4.x, b4.y, b4.z, b4.w};
        #pragma unroll
        for (int n = 0; n < 4; ++n) {
            const int pl = n * 16 + row16;
            const float sc = s_s[pl];
            const float cm2 = cmin_s[pl];
            float* op = outb + pl;
            #pragma unroll
            for (int r = 0; r < 4; ++r) {
                op[(size_t)(ob + r) * HW] =
                    acc[m][n][r] * sc + cm2 * wr[r] + br[r];
            }
        }
    }
}

extern "C" void kernel_launch(void* const* d_in, const int* in_sizes, int n_in,
                              void* d_out, int out_size, void* d_ws, size_t ws_size,
                              hipStream_t stream) {
    const float* x    = (const float*)d_in[0];
    const float* w    = (const float*)d_in[1];
    const float* bias = (const float*)d_in[2];
    float* out = (float*)d_out;

    ushort* w16 = (ushort*)d_ws;                                   // 128 KiB
    float* wsum = (float*)((char*)d_ws + (size_t)CO * CI * sizeof(ushort));

    prep_kernel<<<CO, 64, 0, stream>>>(w, w16, wsum);
    noise_conv_kernel<<<512, 256, 0, stream>>>(x, w16, wsum, bias, out);
}